// Round 8
// baseline (52.508 us; speedup 1.0000x reference)
//
#include <hip/hip_runtime.h>
#include <hip/hip_bf16.h>

typedef __attribute__((ext_vector_type(4))) float f32x4;
typedef __attribute__((ext_vector_type(8))) short bf16x8;

#define NNODES 10000
#define KDIM 512
#define NDIM 512
#define NEDGES 160000

__device__ __forceinline__ unsigned short f2bf(float f) {
    __hip_bfloat16 h = __float2bfloat16(f);
    return *reinterpret_cast<unsigned short*>(&h);
}

// ---- fused prep: x->bf16 (blocks 0..4999), w->bf16 (5000..5255), row_ptr (5256..5295) ----
__global__ __launch_bounds__(256) void prep_kernel(
    const float* __restrict__ x, unsigned short* __restrict__ xb,
    const float* __restrict__ w, unsigned short* __restrict__ wb,
    const int* __restrict__ rows, int* __restrict__ row_ptr) {
    const int b = blockIdx.x;
    if (b < 5000) {
        int i = (b * 256 + threadIdx.x) * 4;
        float4 v = *reinterpret_cast<const float4*>(x + i);
        ushort4 o;
        o.x = f2bf(v.x); o.y = f2bf(v.y); o.z = f2bf(v.z); o.w = f2bf(v.w);
        *reinterpret_cast<ushort4*>(xb + i) = o;
    } else if (b < 5256) {
        int i = ((b - 5000) * 256 + threadIdx.x) * 4;
        float4 v = *reinterpret_cast<const float4*>(w + i);
        ushort4 o;
        o.x = f2bf(v.x); o.y = f2bf(v.y); o.z = f2bf(v.z); o.w = f2bf(v.w);
        *reinterpret_cast<ushort4*>(wb + i) = o;
    } else {
        int i = (b - 5256) * 256 + threadIdx.x;
        if (i <= NNODES) {
            int lo = 0, hi = NEDGES;
            while (lo < hi) { int mid = (lo + hi) >> 1; if (rows[mid] < i) lo = mid + 1; else hi = mid; }
            row_ptr[i] = lo;
        }
    }
}

// ---- bf16 MFMA GEMM: C[M][512] = A[M][512] * B[512][512]^T, C stored as bf16 ----
// BM=64, BN=128, BK=32; double-buffered: STAGE(k+1) issued before compute(k).
__global__ __launch_bounds__(256) void gemm_kernel(const unsigned short* __restrict__ A,
                                                   const unsigned short* __restrict__ B,
                                                   unsigned short* __restrict__ C, int M) {
    __shared__ unsigned short lA[2][64 * 32];
    __shared__ unsigned short lB[2][128 * 32];
    const int tid = threadIdx.x;
    const int wid = tid >> 6;
    const int lane = tid & 63;
    const int wc = wid;
    const int m0 = blockIdx.x * 64;
    const int n0 = blockIdx.y * 128;

    const int arow = tid >> 2, aseg = tid & 3;
    int agrow = m0 + arow; if (agrow > M - 1) agrow = M - 1;

    f32x4 acc[4][2] = {};

#define STAGE(buf, k0)                                                              \
    {                                                                               \
        const unsigned short* ga = A + (size_t)agrow * KDIM + (k0) + aseg * 8;      \
        __builtin_amdgcn_global_load_lds(                                           \
            (const __attribute__((address_space(1))) void*)ga,                      \
            (__attribute__((address_space(3))) void*)(lA[buf] + (size_t)tid * 8),   \
            16, 0, 0);                                                              \
        _Pragma("unroll")                                                           \
        for (int q = 0; q < 2; q++) {                                               \
            int li = q * 256 + tid;                                                 \
            int row = li >> 2, seg = li & 3;                                        \
            const unsigned short* gb = B + (size_t)(n0 + row) * KDIM + (k0) + seg * 8; \
            __builtin_amdgcn_global_load_lds(                                       \
                (const __attribute__((address_space(1))) void*)gb,                  \
                (__attribute__((address_space(3))) void*)(lB[buf] + (size_t)li * 8),\
                16, 0, 0);                                                          \
        }                                                                           \
    }

    STAGE(0, 0)
    int cur = 0;
#pragma unroll
    for (int kt = 0; kt < 16; kt++) {
        __syncthreads();  // barrier drains vmcnt: tile kt landed
        if (kt + 1 < 16) STAGE(cur ^ 1, (kt + 1) * 32)

        bf16x8 af[4], bfr[2];
#pragma unroll
        for (int i = 0; i < 4; i++)
            af[i] = *reinterpret_cast<const bf16x8*>(
                lA[cur] + (size_t)(i * 16 + (lane & 15)) * 32 + (lane >> 4) * 8);
#pragma unroll
        for (int j = 0; j < 2; j++)
            bfr[j] = *reinterpret_cast<const bf16x8*>(
                lB[cur] + (size_t)(wc * 32 + j * 16 + (lane & 15)) * 32 + (lane >> 4) * 8);
#pragma unroll
        for (int i = 0; i < 4; i++)
#pragma unroll
            for (int j = 0; j < 2; j++)
                acc[i][j] = __builtin_amdgcn_mfma_f32_16x16x32_bf16(af[i], bfr[j], acc[i][j], 0, 0, 0);
        cur ^= 1;
    }

#pragma unroll
    for (int i = 0; i < 4; i++) {
#pragma unroll
        for (int r = 0; r < 4; r++) {
            int row = m0 + i * 16 + (lane >> 4) * 4 + r;
            if (row < M) {
#pragma unroll
                for (int j = 0; j < 2; j++) {
                    int col = n0 + wc * 32 + j * 16 + (lane & 15);
                    C[(size_t)row * NDIM + col] = f2bf(acc[i][j][r]);
                }
            }
        }
    }
}

// ---- repack: xfb bf16 -> int8 (per-row absmax scale). 1 wave per row, 4 rows/block ----
__global__ __launch_bounds__(256) void repack_kernel(
    const unsigned short* __restrict__ xfb,
    signed char* __restrict__ x8, float* __restrict__ scales) {
    const int row = blockIdx.x * 4 + (threadIdx.x >> 6);
    const int lane = threadIdx.x & 63;
    uint4 u = *reinterpret_cast<const uint4*>(xfb + (size_t)row * NDIM + lane * 8);
    float f0 = __uint_as_float(u.x << 16), f1 = __uint_as_float(u.x & 0xffff0000u);
    float f2 = __uint_as_float(u.y << 16), f3 = __uint_as_float(u.y & 0xffff0000u);
    float f4 = __uint_as_float(u.z << 16), f5 = __uint_as_float(u.z & 0xffff0000u);
    float f6 = __uint_as_float(u.w << 16), f7 = __uint_as_float(u.w & 0xffff0000u);
    float m = fmaxf(fabsf(f0), fabsf(f1));
    m = fmaxf(m, fmaxf(fabsf(f2), fabsf(f3)));
    m = fmaxf(m, fmaxf(fabsf(f4), fabsf(f5)));
    m = fmaxf(m, fmaxf(fabsf(f6), fabsf(f7)));
#pragma unroll
    for (int off = 32; off; off >>= 1) m = fmaxf(m, __shfl_xor(m, off, 64));
    float mm = (m > 0.f) ? m : 1.f;
    float inv = 127.f / mm;
    int q0 = (int)rintf(f0 * inv), q1 = (int)rintf(f1 * inv);
    int q2 = (int)rintf(f2 * inv), q3 = (int)rintf(f3 * inv);
    int q4 = (int)rintf(f4 * inv), q5 = (int)rintf(f5 * inv);
    int q6 = (int)rintf(f6 * inv), q7 = (int)rintf(f7 * inv);
    uint2 o;
    o.x = (q0 & 255) | ((q1 & 255) << 8) | ((q2 & 255) << 16) | ((unsigned)(q3 & 255) << 24);
    o.y = (q4 & 255) | ((q5 & 255) << 8) | ((q6 & 255) << 16) | ((unsigned)(q7 & 255) << 24);
    *reinterpret_cast<uint2*>(x8 + (size_t)row * NDIM + lane * 8) = o;
    if (lane == 0) scales[row] = mm * (1.f / 127.f);
}

// per-edge accumulate: 4 int8 -> 4 fp32 channels
#define ACC4Q(P, vv, uu)                                          \
    P[0] += (vv) * (float)(signed char)(uu);                      \
    P[1] += (vv) * (float)(signed char)((uu) >> 8);               \
    P[2] += (vv) * (float)(signed char)((uu) >> 16);              \
    P[3] += (vv) * (float)((int)(uu) >> 24);

#define GQ(c) (*reinterpret_cast<const unsigned*>(x8 + (size_t)(c) * NDIM + chbase))

// ---- COO spmm (row_ptr precomputed) + bias + PReLU, int8 gather, channel-split ----
// 10000 waves (2500 blocks): wave = (pair, half). half h covers channels
// [h*256, h*256+256); 4 int8 ch per lane per edge (one 4B load).
// Doubles TLP vs node-pair-only scheme to hide the s_load->gather chain.
__global__ __launch_bounds__(256) void spmm_prelu_kernel(
    const signed char* __restrict__ x8,     // [NNODES][512] int8
    const float* __restrict__ scales,       // [NNODES]
    const float* __restrict__ vals,         // [E]
    const int* __restrict__ row_ptr,        // [NNODES+1]
    const int* __restrict__ cols,           // [E]
    const float* __restrict__ bias,         // [512]
    const float* __restrict__ prelu_a,      // [1]
    float* __restrict__ out) {
    const int lane = threadIdx.x & 63;
    const int gw2 = (blockIdx.x * 256 + threadIdx.x) >> 6;  // 0..9999
    const int h = gw2 & 1;
    const int pair = gw2 >> 1;              // 0..4999
    const int nd0 = pair, nd1 = pair + 5000;
    const int chbase = h * 256 + lane * 4;  // this wave's 4 channels per lane

    const int s0 = __builtin_amdgcn_readfirstlane(row_ptr[nd0]);
    const int e0 = __builtin_amdgcn_readfirstlane(row_ptr[nd0 + 1]);
    const int s1 = __builtin_amdgcn_readfirstlane(row_ptr[nd1]);
    const int e1 = __builtin_amdgcn_readfirstlane(row_ptr[nd1 + 1]);

    float p[4] = {}, q[4] = {};

    int i0 = s0, i1 = s1;
    while ((i0 + 4 <= e0) && (i1 + 4 <= e1)) {
        int   c00 = cols[i0], c01 = cols[i0 + 1], c02 = cols[i0 + 2], c03 = cols[i0 + 3];
        int   c10 = cols[i1], c11 = cols[i1 + 1], c12 = cols[i1 + 2], c13 = cols[i1 + 3];
        float v00 = vals[i0] * scales[c00], v01 = vals[i0 + 1] * scales[c01];
        float v02 = vals[i0 + 2] * scales[c02], v03 = vals[i0 + 3] * scales[c03];
        float v10 = vals[i1] * scales[c10], v11 = vals[i1 + 1] * scales[c11];
        float v12 = vals[i1 + 2] * scales[c12], v13 = vals[i1 + 3] * scales[c13];
        unsigned u00 = GQ(c00), u01 = GQ(c01), u02 = GQ(c02), u03 = GQ(c03);
        unsigned u10 = GQ(c10), u11 = GQ(c11), u12 = GQ(c12), u13 = GQ(c13);
        ACC4Q(p, v00, u00) ACC4Q(p, v01, u01) ACC4Q(p, v02, u02) ACC4Q(p, v03, u03)
        ACC4Q(q, v10, u10) ACC4Q(q, v11, u11) ACC4Q(q, v12, u12) ACC4Q(q, v13, u13)
        i0 += 4; i1 += 4;
    }
    // drain node0
    for (; i0 + 4 <= e0; i0 += 4) {
        int c0 = cols[i0], c1 = cols[i0 + 1], c2 = cols[i0 + 2], c3 = cols[i0 + 3];
        float v0 = vals[i0] * scales[c0], v1 = vals[i0 + 1] * scales[c1];
        float v2 = vals[i0 + 2] * scales[c2], v3 = vals[i0 + 3] * scales[c3];
        unsigned u0 = GQ(c0), u1 = GQ(c1), u2 = GQ(c2), u3 = GQ(c3);
        ACC4Q(p, v0, u0) ACC4Q(p, v1, u1) ACC4Q(p, v2, u2) ACC4Q(p, v3, u3)
    }
    for (; i0 < e0; i0++) {
        int c = cols[i0];
        float v0 = vals[i0] * scales[c];
        unsigned u0 = GQ(c);
        ACC4Q(p, v0, u0)
    }
    // drain node1
    for (; i1 + 4 <= e1; i1 += 4) {
        int c0 = cols[i1], c1 = cols[i1 + 1], c2 = cols[i1 + 2], c3 = cols[i1 + 3];
        float v0 = vals[i1] * scales[c0], v1 = vals[i1 + 1] * scales[c1];
        float v2 = vals[i1 + 2] * scales[c2], v3 = vals[i1 + 3] * scales[c3];
        unsigned u0 = GQ(c0), u1 = GQ(c1), u2 = GQ(c2), u3 = GQ(c3);
        ACC4Q(q, v0, u0) ACC4Q(q, v1, u1) ACC4Q(q, v2, u2) ACC4Q(q, v3, u3)
    }
    for (; i1 < e1; i1++) {
        int c = cols[i1];
        float v0 = vals[i1] * scales[c];
        unsigned u0 = GQ(c);
        ACC4Q(q, v0, u0)
    }

    const float4 bv = *reinterpret_cast<const float4*>(bias + chbase);
    const float al = prelu_a[0];

#define EPILOGUE(P, node)                                                        \
    {                                                                            \
        float o0 = P[0] + bv.x, o1 = P[1] + bv.y, o2 = P[2] + bv.z, o3 = P[3] + bv.w; \
        o0 = (o0 >= 0.f) ? o0 : al * o0;                                         \
        o1 = (o1 >= 0.f) ? o1 : al * o1;                                         \
        o2 = (o2 >= 0.f) ? o2 : al * o2;                                         \
        o3 = (o3 >= 0.f) ? o3 : al * o3;                                         \
        f32x4 r0; r0[0] = o0; r0[1] = o1; r0[2] = o2; r0[3] = o3;                \
        f32x4* op = reinterpret_cast<f32x4*>(out + (size_t)(node) * NDIM + chbase); \
        __builtin_nontemporal_store(r0, op);                                     \
    }

    EPILOGUE(p, nd0)
    EPILOGUE(q, nd1)
}

extern "C" void kernel_launch(void* const* d_in, const int* in_sizes, int n_in,
                              void* d_out, int out_size, void* d_ws, size_t ws_size,
                              hipStream_t stream) {
    const float* x        = (const float*)d_in[0];
    const float* fc_w     = (const float*)d_in[1];
    const float* bias     = (const float*)d_in[2];
    const float* prelu_a  = (const float*)d_in[3];
    const float* adj_vals = (const float*)d_in[4];
    const int*   adj_row  = (const int*)d_in[5];
    const int*   adj_col  = (const int*)d_in[6];
    float* out = (float*)d_out;

    char* ws = (char*)d_ws;
    unsigned short* xb  = (unsigned short*)ws;                         // @0,        10,240,000 B
    unsigned short* wb  = (unsigned short*)(ws + 10240000);            // @10240000,    524,288 B
    unsigned short* xfb = (unsigned short*)(ws + 10764288);            // @10764288, 10,240,000 B
    int* row_ptr        = (int*)(ws + 21004288);                       // @21004288,     40,192 B (padded)
    signed char* x8     = (signed char*)(ws + 21044480);               // @21044480,  5,120,000 B
    float* scales       = (float*)(ws + 26164480);                     // @26164480,     40,000 B

    prep_kernel<<<5296, 256, 0, stream>>>(x, xb, fc_w, wb, adj_row, row_ptr);

    dim3 ggrid((NNODES + 63) / 64, NDIM / 128);
    gemm_kernel<<<ggrid, 256, 0, stream>>>(xb, wb, xfb, NNODES);

    repack_kernel<<<NNODES / 4, 256, 0, stream>>>(xfb, x8, scales);

    spmm_prelu_kernel<<<2500, 256, 0, stream>>>(x8, scales, adj_vals, row_ptr, adj_col,
                                                bias, prelu_a, out);
}

// Round 9
// 49.684 us; speedup vs baseline: 1.0568x; 1.0568x over previous
//
#include <hip/hip_runtime.h>
#include <hip/hip_bf16.h>

typedef __attribute__((ext_vector_type(4))) float f32x4;
typedef __attribute__((ext_vector_type(8))) short bf16x8;

#define NNODES 10000
#define KDIM 512
#define NDIM 512
#define NEDGES 160000

__device__ __forceinline__ unsigned short f2bf(float f) {
    __hip_bfloat16 h = __float2bfloat16(f);
    return *reinterpret_cast<unsigned short*>(&h);
}

// ---- fused prep: x->bf16 (blocks 0..4999), w->bf16 (5000..5255), row_ptr (5256..5295) ----
__global__ __launch_bounds__(256) void prep_kernel(
    const float* __restrict__ x, unsigned short* __restrict__ xb,
    const float* __restrict__ w, unsigned short* __restrict__ wb,
    const int* __restrict__ rows, int* __restrict__ row_ptr) {
    const int b = blockIdx.x;
    if (b < 5000) {
        int i = (b * 256 + threadIdx.x) * 4;
        float4 v = *reinterpret_cast<const float4*>(x + i);
        ushort4 o;
        o.x = f2bf(v.x); o.y = f2bf(v.y); o.z = f2bf(v.z); o.w = f2bf(v.w);
        *reinterpret_cast<ushort4*>(xb + i) = o;
    } else if (b < 5256) {
        int i = ((b - 5000) * 256 + threadIdx.x) * 4;
        float4 v = *reinterpret_cast<const float4*>(w + i);
        ushort4 o;
        o.x = f2bf(v.x); o.y = f2bf(v.y); o.z = f2bf(v.z); o.w = f2bf(v.w);
        *reinterpret_cast<ushort4*>(wb + i) = o;
    } else {
        int i = (b - 5256) * 256 + threadIdx.x;
        if (i <= NNODES) {
            int lo = 0, hi = NEDGES;
            while (lo < hi) { int mid = (lo + hi) >> 1; if (rows[mid] < i) lo = mid + 1; else hi = mid; }
            row_ptr[i] = lo;
        }
    }
}

// ---- bf16 MFMA GEMM: C[M][512] = A[M][512] * B[512][512]^T, C stored as bf16 ----
// BM=64, BN=128, BK=64; 8 K-steps, double-buffered.
// LDS XOR-swizzle (T2, rule-#21 form): linear LDS dest for global_load_lds,
// inverse-swizzled GLOBAL source seg, swizzled ds_read address. Kills the 8-way
// bank conflict of row-strided fragment reads (16 lanes x row*128B -> same banks).
__global__ __launch_bounds__(256) void gemm_kernel(const unsigned short* __restrict__ A,
                                                   const unsigned short* __restrict__ B,
                                                   unsigned short* __restrict__ C, int M) {
    __shared__ unsigned short lA[2][64 * 64];    // 16 KB total
    __shared__ unsigned short lB[2][128 * 64];   // 32 KB total
    const int tid = threadIdx.x;
    const int wid = tid >> 6;
    const int lane = tid & 63;
    const int wc = wid;                          // 4 waves across BN=128 (32 cols each)
    const int m0 = blockIdx.x * 64;
    const int n0 = blockIdx.y * 128;

    f32x4 acc[4][2] = {};

    // stage: LDS slot (row, pseg) holds global seg gseg = pseg ^ (row&7)
#define STAGE(buf, k0)                                                                 \
    {                                                                                  \
        _Pragma("unroll")                                                              \
        for (int t = 0; t < 2; t++) {                                                  \
            int li = t * 256 + tid;                                                    \
            int row = li >> 3, pseg = li & 7;                                          \
            int gseg = pseg ^ (row & 7);                                               \
            int grow = m0 + row; if (grow > M - 1) grow = M - 1;                       \
            const unsigned short* ga = A + (size_t)grow * KDIM + (k0) + gseg * 8;      \
            __builtin_amdgcn_global_load_lds(                                          \
                (const __attribute__((address_space(1))) void*)ga,                     \
                (__attribute__((address_space(3))) void*)(lA[buf] + (size_t)li * 8),   \
                16, 0, 0);                                                             \
        }                                                                              \
        _Pragma("unroll")                                                              \
        for (int t = 0; t < 4; t++) {                                                  \
            int li = t * 256 + tid;                                                    \
            int row = li >> 3, pseg = li & 7;                                          \
            int gseg = pseg ^ (row & 7);                                               \
            const unsigned short* gb = B + (size_t)(n0 + row) * KDIM + (k0) + gseg * 8;\
            __builtin_amdgcn_global_load_lds(                                          \
                (const __attribute__((address_space(1))) void*)gb,                     \
                (__attribute__((address_space(3))) void*)(lB[buf] + (size_t)li * 8),   \
                16, 0, 0);                                                             \
        }                                                                              \
    }

    STAGE(0, 0)
    int cur = 0;
#pragma unroll
    for (int kt = 0; kt < 8; kt++) {
        __syncthreads();  // barrier drains vmcnt: tile kt landed
        if (kt + 1 < 8) STAGE(cur ^ 1, (kt + 1) * 64)

        bf16x8 af[4][2], bfr[2][2];
#pragma unroll
        for (int i = 0; i < 4; i++)
#pragma unroll
            for (int h = 0; h < 2; h++) {
                int row = i * 16 + (lane & 15);
                int s = (lane >> 4) + h * 4;
                af[i][h] = *reinterpret_cast<const bf16x8*>(
                    lA[cur] + (size_t)row * 64 + (size_t)(s ^ (row & 7)) * 8);
            }
#pragma unroll
        for (int j = 0; j < 2; j++)
#pragma unroll
            for (int h = 0; h < 2; h++) {
                int row = wc * 32 + j * 16 + (lane & 15);
                int s = (lane >> 4) + h * 4;
                bfr[j][h] = *reinterpret_cast<const bf16x8*>(
                    lB[cur] + (size_t)row * 64 + (size_t)(s ^ (row & 7)) * 8);
            }
#pragma unroll
        for (int h = 0; h < 2; h++)
#pragma unroll
            for (int i = 0; i < 4; i++)
#pragma unroll
                for (int j = 0; j < 2; j++)
                    acc[i][j] = __builtin_amdgcn_mfma_f32_16x16x32_bf16(af[i][h], bfr[j][h], acc[i][j], 0, 0, 0);
        cur ^= 1;
    }

#pragma unroll
    for (int i = 0; i < 4; i++) {
#pragma unroll
        for (int r = 0; r < 4; r++) {
            int row = m0 + i * 16 + (lane >> 4) * 4 + r;
            if (row < M) {
#pragma unroll
                for (int j = 0; j < 2; j++) {
                    int col = n0 + wc * 32 + j * 16 + (lane & 15);
                    C[(size_t)row * NDIM + col] = f2bf(acc[i][j][r]);
                }
            }
        }
    }
}

// per-edge accumulate: 8 bf16x2 words -> 8 fp32 channels
#define ACC8(P, vv, uu)                                      \
    P[0] += (vv) * __uint_as_float((uu).x << 16);            \
    P[1] += (vv) * __uint_as_float((uu).x & 0xffff0000u);    \
    P[2] += (vv) * __uint_as_float((uu).y << 16);            \
    P[3] += (vv) * __uint_as_float((uu).y & 0xffff0000u);    \
    P[4] += (vv) * __uint_as_float((uu).z << 16);            \
    P[5] += (vv) * __uint_as_float((uu).z & 0xffff0000u);    \
    P[6] += (vv) * __uint_as_float((uu).w << 16);            \
    P[7] += (vv) * __uint_as_float((uu).w & 0xffff0000u);

#define GATHER(c) (*reinterpret_cast<const uint4*>(xb + (size_t)(c) * NDIM + lane * 8))

// ---- COO spmm (row_ptr precomputed) + bias + PReLU, bf16 gather (R5 structure) ----
// 5000 waves, each owns nodes {gw, gw+5000}, interleaved 4+4 edges per iter.
__global__ __launch_bounds__(256) void spmm_prelu_kernel(
    const unsigned short* __restrict__ xb,  // [NNODES][512] bf16
    const float* __restrict__ vals,         // [E]
    const int* __restrict__ row_ptr,        // [NNODES+1]
    const int* __restrict__ cols,           // [E]
    const float* __restrict__ bias,         // [512]
    const float* __restrict__ prelu_a,      // [1]
    float* __restrict__ out) {
    const int lane = threadIdx.x & 63;
    const int gw = (blockIdx.x * 256 + threadIdx.x) >> 6;  // 0..4999
    const int nd0 = gw, nd1 = gw + 5000;

    const int s0 = __builtin_amdgcn_readfirstlane(row_ptr[nd0]);
    const int e0 = __builtin_amdgcn_readfirstlane(row_ptr[nd0 + 1]);
    const int s1 = __builtin_amdgcn_readfirstlane(row_ptr[nd1]);
    const int e1 = __builtin_amdgcn_readfirstlane(row_ptr[nd1 + 1]);

    float p[8] = {}, q[8] = {};

    int i0 = s0, i1 = s1;
    while ((i0 + 4 <= e0) && (i1 + 4 <= e1)) {
        float v00 = vals[i0], v01 = vals[i0 + 1], v02 = vals[i0 + 2], v03 = vals[i0 + 3];
        int   c00 = cols[i0], c01 = cols[i0 + 1], c02 = cols[i0 + 2], c03 = cols[i0 + 3];
        float v10 = vals[i1], v11 = vals[i1 + 1], v12 = vals[i1 + 2], v13 = vals[i1 + 3];
        int   c10 = cols[i1], c11 = cols[i1 + 1], c12 = cols[i1 + 2], c13 = cols[i1 + 3];
        uint4 u00 = GATHER(c00), u01 = GATHER(c01), u02 = GATHER(c02), u03 = GATHER(c03);
        uint4 u10 = GATHER(c10), u11 = GATHER(c11), u12 = GATHER(c12), u13 = GATHER(c13);
        ACC8(p, v00, u00) ACC8(p, v01, u01) ACC8(p, v02, u02) ACC8(p, v03, u03)
        ACC8(q, v10, u10) ACC8(q, v11, u11) ACC8(q, v12, u12) ACC8(q, v13, u13)
        i0 += 4; i1 += 4;
    }
    // drain node0
    for (; i0 + 4 <= e0; i0 += 4) {
        float v0 = vals[i0], v1 = vals[i0 + 1], v2 = vals[i0 + 2], v3 = vals[i0 + 3];
        uint4 u0 = GATHER(cols[i0]), u1 = GATHER(cols[i0 + 1]);
        uint4 u2 = GATHER(cols[i0 + 2]), u3 = GATHER(cols[i0 + 3]);
        ACC8(p, v0, u0) ACC8(p, v1, u1) ACC8(p, v2, u2) ACC8(p, v3, u3)
    }
    for (; i0 < e0; i0++) {
        float v0 = vals[i0]; uint4 u0 = GATHER(cols[i0]);
        ACC8(p, v0, u0)
    }
    // drain node1
    for (; i1 + 4 <= e1; i1 += 4) {
        float v0 = vals[i1], v1 = vals[i1 + 1], v2 = vals[i1 + 2], v3 = vals[i1 + 3];
        uint4 u0 = GATHER(cols[i1]), u1 = GATHER(cols[i1 + 1]);
        uint4 u2 = GATHER(cols[i1 + 2]), u3 = GATHER(cols[i1 + 3]);
        ACC8(q, v0, u0) ACC8(q, v1, u1) ACC8(q, v2, u2) ACC8(q, v3, u3)
    }
    for (; i1 < e1; i1++) {
        float v0 = vals[i1]; uint4 u0 = GATHER(cols[i1]);
        ACC8(q, v0, u0)
    }

    const float4* b4 = reinterpret_cast<const float4*>(bias + lane * 8);
    const float4 bA = b4[0], bB = b4[1];
    const float al = prelu_a[0];

#define EPILOGUE(P, node)                                                        \
    {                                                                            \
        float o0 = P[0] + bA.x, o1 = P[1] + bA.y, o2 = P[2] + bA.z, o3 = P[3] + bA.w; \
        float o4 = P[4] + bB.x, o5 = P[5] + bB.y, o6 = P[6] + bB.z, o7 = P[7] + bB.w; \
        o0 = (o0 >= 0.f) ? o0 : al * o0;                                         \
        o1 = (o1 >= 0.f) ? o1 : al * o1;                                         \
        o2 = (o2 >= 0.f) ? o2 : al * o2;                                         \
        o3 = (o3 >= 0.f) ? o3 : al * o3;                                         \
        o4 = (o4 >= 0.f) ? o4 : al * o4;                                         \
        o5 = (o5 >= 0.f) ? o5 : al * o5;                                         \
        o6 = (o6 >= 0.f) ? o6 : al * o6;                                         \
        o7 = (o7 >= 0.f) ? o7 : al * o7;                                         \
        f32x4 r0; r0[0] = o0; r0[1] = o1; r0[2] = o2; r0[3] = o3;                \
        f32x4 r1; r1[0] = o4; r1[1] = o5; r1[2] = o6; r1[3] = o7;                \
        f32x4* op = reinterpret_cast<f32x4*>(out + (size_t)(node) * NDIM + lane * 8); \
        __builtin_nontemporal_store(r0, op);                                     \
        __builtin_nontemporal_store(r1, op + 1);                                 \
    }

    EPILOGUE(p, nd0)
    EPILOGUE(q, nd1)
}

extern "C" void kernel_launch(void* const* d_in, const int* in_sizes, int n_in,
                              void* d_out, int out_size, void* d_ws, size_t ws_size,
                              hipStream_t stream) {
    const float* x        = (const float*)d_in[0];
    const float* fc_w     = (const float*)d_in[1];
    const float* bias     = (const float*)d_in[2];
    const float* prelu_a  = (const float*)d_in[3];
    const float* adj_vals = (const float*)d_in[4];
    const int*   adj_row  = (const int*)d_in[5];
    const int*   adj_col  = (const int*)d_in[6];
    float* out = (float*)d_out;

    char* ws = (char*)d_ws;
    unsigned short* xb  = (unsigned short*)ws;                        // @0,        10,240,000 B
    unsigned short* wb  = (unsigned short*)(ws + 10240000);           // @10240000,    524,288 B
    unsigned short* xfb = (unsigned short*)(ws + 10764288);           // @10764288, 10,240,000 B
    int* row_ptr        = (int*)(ws + 21004288);                      // @21004288,     40,192 B

    prep_kernel<<<5296, 256, 0, stream>>>(x, xb, fc_w, wb, adj_row, row_ptr);

    dim3 ggrid((NNODES + 63) / 64, NDIM / 128);
    gemm_kernel<<<ggrid, 256, 0, stream>>>(xb, wb, xfb, NNODES);

    spmm_prelu_kernel<<<1250, 256, 0, stream>>>(xfb, adj_vals, row_ptr, adj_col,
                                                bias, prelu_a, out);
}

// Round 10
// 46.169 us; speedup vs baseline: 1.1373x; 1.0761x over previous
//
#include <hip/hip_runtime.h>
#include <hip/hip_bf16.h>

typedef __attribute__((ext_vector_type(4))) float f32x4;
typedef __attribute__((ext_vector_type(8))) short bf16x8;

#define NNODES 10000
#define KDIM 512
#define NDIM 512
#define NEDGES 160000
#define GEMM_BLOCKS 628   // 157 mb x 4 nb
#define RP_BLOCKS 40      // rowptr: 40*256 = 10240 >= 10001

__device__ __forceinline__ unsigned short f2bf(float f) {
    __hip_bfloat16 h = __float2bfloat16(f);
    return *reinterpret_cast<unsigned short*>(&h);
}

__device__ __forceinline__ bf16x8 cvt8(float4 a, float4 b) {
    bf16x8 r;
    r[0] = (short)f2bf(a.x); r[1] = (short)f2bf(a.y);
    r[2] = (short)f2bf(a.z); r[3] = (short)f2bf(a.w);
    r[4] = (short)f2bf(b.x); r[5] = (short)f2bf(b.y);
    r[6] = (short)f2bf(b.z); r[7] = (short)f2bf(b.w);
    return r;
}

// ---- fused GEMM (fp32 in, bf16 MFMA, bf16 out) + rowptr side-blocks ----
// C[M][512] = bf16(A[M][512] fp32) * bf16(B[512][512] fp32)^T
// BM=64, BN=128, BK=64, 8 K-steps, double-buffered reg-staging:
//   global fp32 -> regs -> cvt bf16 -> ds_write_b128 at XOR-swizzled slot.
// One barrier per K-step (write to buf^1 while buf is read).
__global__ __launch_bounds__(256) void gemm_rowptr_kernel(
    const float* __restrict__ A, const float* __restrict__ B,
    unsigned short* __restrict__ C,
    const int* __restrict__ rows, int* __restrict__ row_ptr, int M) {
    __shared__ unsigned short lA[2][64 * 64];    // 16 KB
    __shared__ unsigned short lB[2][128 * 64];   // 32 KB

    if (blockIdx.x >= GEMM_BLOCKS) {
        int i = (blockIdx.x - GEMM_BLOCKS) * 256 + threadIdx.x;
        if (i <= NNODES) {
            int lo = 0, hi = NEDGES;
            while (lo < hi) { int mid = (lo + hi) >> 1; if (rows[mid] < i) lo = mid + 1; else hi = mid; }
            row_ptr[i] = lo;
        }
        return;
    }

    const int tid = threadIdx.x;
    const int wid = tid >> 6;
    const int lane = tid & 63;
    const int wc = wid;                          // 4 waves across BN=128
    const int m0 = (blockIdx.x >> 2) * 64;
    const int n0 = (blockIdx.x & 3) * 128;

    // A staging: segs s = tid, tid+256 over 64 rows x 8 segs (8 fp32 cols/seg)
    const int ar0 = tid >> 3, ar1 = (tid + 256) >> 3;
    const int ag = tid & 7;
    int agr0 = m0 + ar0; if (agr0 >= M) agr0 = M - 1;
    int agr1 = m0 + ar1; if (agr1 >= M) agr1 = M - 1;
    const float* pa0 = A + (size_t)agr0 * KDIM + ag * 8;
    const float* pa1 = A + (size_t)agr1 * KDIM + ag * 8;
    const int wA0 = ar0 * 64 + (ag ^ (ar0 & 7)) * 8;   // ushort offset
    const int wA1 = ar1 * 64 + (ag ^ (ar1 & 7)) * 8;
    // B staging: segs s = tid + 256k, rows br+32k (32 | 8 so swizzle bits equal)
    const int br = tid >> 3;
    const float* pb0 = B + (size_t)(n0 + br) * KDIM + ag * 8;
    const float* pb1 = B + (size_t)(n0 + br + 32) * KDIM + ag * 8;
    const float* pb2 = B + (size_t)(n0 + br + 64) * KDIM + ag * 8;
    const float* pb3 = B + (size_t)(n0 + br + 96) * KDIM + ag * 8;
    const int wB = br * 64 + (ag ^ (br & 7)) * 8;

    f32x4 acc[4][2] = {};
    float4 la0, la1, la2, la3, lb0, lb1, lb2, lb3, lb4, lb5, lb6, lb7;

#define GLOAD(k0)                                                \
    la0 = *reinterpret_cast<const float4*>(pa0 + (k0));          \
    la1 = *reinterpret_cast<const float4*>(pa0 + (k0) + 4);      \
    la2 = *reinterpret_cast<const float4*>(pa1 + (k0));          \
    la3 = *reinterpret_cast<const float4*>(pa1 + (k0) + 4);      \
    lb0 = *reinterpret_cast<const float4*>(pb0 + (k0));          \
    lb1 = *reinterpret_cast<const float4*>(pb0 + (k0) + 4);      \
    lb2 = *reinterpret_cast<const float4*>(pb1 + (k0));          \
    lb3 = *reinterpret_cast<const float4*>(pb1 + (k0) + 4);      \
    lb4 = *reinterpret_cast<const float4*>(pb2 + (k0));          \
    lb5 = *reinterpret_cast<const float4*>(pb2 + (k0) + 4);      \
    lb6 = *reinterpret_cast<const float4*>(pb3 + (k0));          \
    lb7 = *reinterpret_cast<const float4*>(pb3 + (k0) + 4);

#define LWRITE(buf)                                                          \
    *reinterpret_cast<bf16x8*>(lA[buf] + wA0) = cvt8(la0, la1);              \
    *reinterpret_cast<bf16x8*>(lA[buf] + wA1) = cvt8(la2, la3);              \
    *reinterpret_cast<bf16x8*>(lB[buf] + wB) = cvt8(lb0, lb1);               \
    *reinterpret_cast<bf16x8*>(lB[buf] + wB + 32 * 64) = cvt8(lb2, lb3);     \
    *reinterpret_cast<bf16x8*>(lB[buf] + wB + 64 * 64) = cvt8(lb4, lb5);     \
    *reinterpret_cast<bf16x8*>(lB[buf] + wB + 96 * 64) = cvt8(lb6, lb7);

    GLOAD(0)
    LWRITE(0)
    __syncthreads();
    int cur = 0;
#pragma unroll
    for (int kt = 0; kt < 8; kt++) {
        if (kt + 1 < 8) { GLOAD((kt + 1) * 64) }

        bf16x8 af[4][2], bfr[2][2];
#pragma unroll
        for (int i = 0; i < 4; i++)
#pragma unroll
            for (int h = 0; h < 2; h++) {
                int row = i * 16 + (lane & 15);
                int s = (lane >> 4) + h * 4;
                af[i][h] = *reinterpret_cast<const bf16x8*>(
                    lA[cur] + (size_t)row * 64 + (size_t)(s ^ (row & 7)) * 8);
            }
#pragma unroll
        for (int j = 0; j < 2; j++)
#pragma unroll
            for (int h = 0; h < 2; h++) {
                int row = wc * 32 + j * 16 + (lane & 15);
                int s = (lane >> 4) + h * 4;
                bfr[j][h] = *reinterpret_cast<const bf16x8*>(
                    lB[cur] + (size_t)row * 64 + (size_t)(s ^ (row & 7)) * 8);
            }
#pragma unroll
        for (int h = 0; h < 2; h++)
#pragma unroll
            for (int i = 0; i < 4; i++)
#pragma unroll
                for (int j = 0; j < 2; j++)
                    acc[i][j] = __builtin_amdgcn_mfma_f32_16x16x32_bf16(af[i][h], bfr[j][h], acc[i][j], 0, 0, 0);

        if (kt + 1 < 8) { LWRITE(cur ^ 1) }
        __syncthreads();
        cur ^= 1;
    }

#pragma unroll
    for (int i = 0; i < 4; i++) {
#pragma unroll
        for (int r = 0; r < 4; r++) {
            int row = m0 + i * 16 + (lane >> 4) * 4 + r;
            if (row < M) {
#pragma unroll
                for (int j = 0; j < 2; j++) {
                    int col = n0 + wc * 32 + j * 16 + (lane & 15);
                    C[(size_t)row * NDIM + col] = f2bf(acc[i][j][r]);
                }
            }
        }
    }
}

// per-edge accumulate: 8 bf16x2 words -> 8 fp32 channels
#define ACC8(P, vv, uu)                                      \
    P[0] += (vv) * __uint_as_float((uu).x << 16);            \
    P[1] += (vv) * __uint_as_float((uu).x & 0xffff0000u);    \
    P[2] += (vv) * __uint_as_float((uu).y << 16);            \
    P[3] += (vv) * __uint_as_float((uu).y & 0xffff0000u);    \
    P[4] += (vv) * __uint_as_float((uu).z << 16);            \
    P[5] += (vv) * __uint_as_float((uu).z & 0xffff0000u);    \
    P[6] += (vv) * __uint_as_float((uu).w << 16);            \
    P[7] += (vv) * __uint_as_float((uu).w & 0xffff0000u);

#define GATHER(c) (*reinterpret_cast<const uint4*>(xb + (size_t)(c) * NDIM + lane * 8))

// ---- COO spmm (row_ptr precomputed) + bias + PReLU, bf16 gather (R5 structure) ----
__global__ __launch_bounds__(256) void spmm_prelu_kernel(
    const unsigned short* __restrict__ xb,  // [NNODES][512] bf16
    const float* __restrict__ vals,         // [E]
    const int* __restrict__ row_ptr,        // [NNODES+1]
    const int* __restrict__ cols,           // [E]
    const float* __restrict__ bias,         // [512]
    const float* __restrict__ prelu_a,      // [1]
    float* __restrict__ out) {
    const int lane = threadIdx.x & 63;
    const int gw = (blockIdx.x * 256 + threadIdx.x) >> 6;  // 0..4999
    const int nd0 = gw, nd1 = gw + 5000;

    const int s0 = __builtin_amdgcn_readfirstlane(row_ptr[nd0]);
    const int e0 = __builtin_amdgcn_readfirstlane(row_ptr[nd0 + 1]);
    const int s1 = __builtin_amdgcn_readfirstlane(row_ptr[nd1]);
    const int e1 = __builtin_amdgcn_readfirstlane(row_ptr[nd1 + 1]);

    float p[8] = {}, q[8] = {};

    int i0 = s0, i1 = s1;
    while ((i0 + 4 <= e0) && (i1 + 4 <= e1)) {
        float v00 = vals[i0], v01 = vals[i0 + 1], v02 = vals[i0 + 2], v03 = vals[i0 + 3];
        int   c00 = cols[i0], c01 = cols[i0 + 1], c02 = cols[i0 + 2], c03 = cols[i0 + 3];
        float v10 = vals[i1], v11 = vals[i1 + 1], v12 = vals[i1 + 2], v13 = vals[i1 + 3];
        int   c10 = cols[i1], c11 = cols[i1 + 1], c12 = cols[i1 + 2], c13 = cols[i1 + 3];
        uint4 u00 = GATHER(c00), u01 = GATHER(c01), u02 = GATHER(c02), u03 = GATHER(c03);
        uint4 u10 = GATHER(c10), u11 = GATHER(c11), u12 = GATHER(c12), u13 = GATHER(c13);
        ACC8(p, v00, u00) ACC8(p, v01, u01) ACC8(p, v02, u02) ACC8(p, v03, u03)
        ACC8(q, v10, u10) ACC8(q, v11, u11) ACC8(q, v12, u12) ACC8(q, v13, u13)
        i0 += 4; i1 += 4;
    }
    for (; i0 + 4 <= e0; i0 += 4) {
        float v0 = vals[i0], v1 = vals[i0 + 1], v2 = vals[i0 + 2], v3 = vals[i0 + 3];
        uint4 u0 = GATHER(cols[i0]), u1 = GATHER(cols[i0 + 1]);
        uint4 u2 = GATHER(cols[i0 + 2]), u3 = GATHER(cols[i0 + 3]);
        ACC8(p, v0, u0) ACC8(p, v1, u1) ACC8(p, v2, u2) ACC8(p, v3, u3)
    }
    for (; i0 < e0; i0++) {
        float v0 = vals[i0]; uint4 u0 = GATHER(cols[i0]);
        ACC8(p, v0, u0)
    }
    for (; i1 + 4 <= e1; i1 += 4) {
        float v0 = vals[i1], v1 = vals[i1 + 1], v2 = vals[i1 + 2], v3 = vals[i1 + 3];
        uint4 u0 = GATHER(cols[i1]), u1 = GATHER(cols[i1 + 1]);
        uint4 u2 = GATHER(cols[i1 + 2]), u3 = GATHER(cols[i1 + 3]);
        ACC8(q, v0, u0) ACC8(q, v1, u1) ACC8(q, v2, u2) ACC8(q, v3, u3)
    }
    for (; i1 < e1; i1++) {
        float v0 = vals[i1]; uint4 u0 = GATHER(cols[i1]);
        ACC8(q, v0, u0)
    }

    const float4* b4 = reinterpret_cast<const float4*>(bias + lane * 8);
    const float4 bA = b4[0], bB = b4[1];
    const float al = prelu_a[0];

#define EPILOGUE(P, node)                                                        \
    {                                                                            \
        float o0 = P[0] + bA.x, o1 = P[1] + bA.y, o2 = P[2] + bA.z, o3 = P[3] + bA.w; \
        float o4 = P[4] + bB.x, o5 = P[5] + bB.y, o6 = P[6] + bB.z, o7 = P[7] + bB.w; \
        o0 = (o0 >= 0.f) ? o0 : al * o0;                                         \
        o1 = (o1 >= 0.f) ? o1 : al * o1;                                         \
        o2 = (o2 >= 0.f) ? o2 : al * o2;                                         \
        o3 = (o3 >= 0.f) ? o3 : al * o3;                                         \
        o4 = (o4 >= 0.f) ? o4 : al * o4;                                         \
        o5 = (o5 >= 0.f) ? o5 : al * o5;                                         \
        o6 = (o6 >= 0.f) ? o6 : al * o6;                                         \
        o7 = (o7 >= 0.f) ? o7 : al * o7;                                         \
        f32x4 r0; r0[0] = o0; r0[1] = o1; r0[2] = o2; r0[3] = o3;                \
        f32x4 r1; r1[0] = o4; r1[1] = o5; r1[2] = o6; r1[3] = o7;                \
        f32x4* op = reinterpret_cast<f32x4*>(out + (size_t)(node) * NDIM + lane * 8); \
        __builtin_nontemporal_store(r0, op);                                     \
        __builtin_nontemporal_store(r1, op + 1);                                 \
    }

    EPILOGUE(p, nd0)
    EPILOGUE(q, nd1)
}

extern "C" void kernel_launch(void* const* d_in, const int* in_sizes, int n_in,
                              void* d_out, int out_size, void* d_ws, size_t ws_size,
                              hipStream_t stream) {
    const float* x        = (const float*)d_in[0];
    const float* fc_w     = (const float*)d_in[1];
    const float* bias     = (const float*)d_in[2];
    const float* prelu_a  = (const float*)d_in[3];
    const float* adj_vals = (const float*)d_in[4];
    const int*   adj_row  = (const int*)d_in[5];
    const int*   adj_col  = (const int*)d_in[6];
    float* out = (float*)d_out;

    char* ws = (char*)d_ws;
    unsigned short* xfb = (unsigned short*)ws;          // @0,        10,240,000 B
    int* row_ptr        = (int*)(ws + 10240000);        // @10240000,     40,064 B

    gemm_rowptr_kernel<<<GEMM_BLOCKS + RP_BLOCKS, 256, 0, stream>>>(
        x, fc_w, xfb, adj_row, row_ptr, NNODES);

    spmm_prelu_kernel<<<1250, 256, 0, stream>>>(xfb, adj_vals, row_ptr, adj_col,
                                                bias, prelu_a, out);
}

// Round 11
// 45.449 us; speedup vs baseline: 1.1553x; 1.0158x over previous
//
#include <hip/hip_runtime.h>
#include <hip/hip_bf16.h>

typedef __attribute__((ext_vector_type(4))) float f32x4;
typedef __attribute__((ext_vector_type(8))) short bf16x8;

#define NNODES 10000
#define KDIM 512
#define NDIM 512
#define NEDGES 160000
#define GEMM_BLOCKS 628   // 157 mb x 4 nb
#define RP_BLOCKS 40      // rowptr: 40*256 = 10240 >= 10001

__device__ __forceinline__ unsigned short f2bf(float f) {
    __hip_bfloat16 h = __float2bfloat16(f);
    return *reinterpret_cast<unsigned short*>(&h);
}

__device__ __forceinline__ bf16x8 cvt8(float4 a, float4 b) {
    bf16x8 r;
    r[0] = (short)f2bf(a.x); r[1] = (short)f2bf(a.y);
    r[2] = (short)f2bf(a.z); r[3] = (short)f2bf(a.w);
    r[4] = (short)f2bf(b.x); r[5] = (short)f2bf(b.y);
    r[6] = (short)f2bf(b.z); r[7] = (short)f2bf(b.w);
    return r;
}

// ---- fused GEMM (fp32 in, bf16 MFMA, bf16 out) + rowptr side-blocks ----
// BM=64, BN=128, BK=64, 8 K-steps, double-buffered reg-staging with XOR-swizzled
// LDS writes. Bijective XCD swizzle (m204): consecutive logical tiles (same A
// panel, 4 n-blocks) land on ONE XCD's L2 -> A fp32 re-reads become L2 hits.
__global__ __launch_bounds__(256) void gemm_rowptr_kernel(
    const float* __restrict__ A, const float* __restrict__ B,
    unsigned short* __restrict__ C,
    const int* __restrict__ rows, int* __restrict__ row_ptr, int M) {
    __shared__ unsigned short lA[2][64 * 64];    // 16 KB
    __shared__ unsigned short lB[2][128 * 64];   // 32 KB

    if (blockIdx.x >= GEMM_BLOCKS) {
        int i = (blockIdx.x - GEMM_BLOCKS) * 256 + threadIdx.x;
        if (i <= NNODES) {
            int lo = 0, hi = NEDGES;
            while (lo < hi) { int mid = (lo + hi) >> 1; if (rows[mid] < i) lo = mid + 1; else hi = mid; }
            row_ptr[i] = lo;
        }
        return;
    }

    // m204 bijective XCD swizzle: nwg=628, q=78, r=4
    const int orig = blockIdx.x;
    const int xcd = orig & 7;
    const int base = (xcd < 4) ? xcd * 79 : 4 * 79 + (xcd - 4) * 78;
    const int wgid = base + (orig >> 3);

    const int tid = threadIdx.x;
    const int wid = tid >> 6;
    const int lane = tid & 63;
    const int wc = wid;                          // 4 waves across BN=128
    const int m0 = (wgid >> 2) * 64;
    const int n0 = (wgid & 3) * 128;

    // A staging: segs s = tid, tid+256 over 64 rows x 8 segs (8 fp32 cols/seg)
    const int ar0 = tid >> 3, ar1 = (tid + 256) >> 3;
    const int ag = tid & 7;
    int agr0 = m0 + ar0; if (agr0 >= M) agr0 = M - 1;
    int agr1 = m0 + ar1; if (agr1 >= M) agr1 = M - 1;
    const float* pa0 = A + (size_t)agr0 * KDIM + ag * 8;
    const float* pa1 = A + (size_t)agr1 * KDIM + ag * 8;
    const int wA0 = ar0 * 64 + (ag ^ (ar0 & 7)) * 8;   // ushort offset
    const int wA1 = ar1 * 64 + (ag ^ (ar1 & 7)) * 8;
    // B staging: rows br+32k (32 | 8 so swizzle bits equal)
    const int br = tid >> 3;
    const float* pb0 = B + (size_t)(n0 + br) * KDIM + ag * 8;
    const float* pb1 = B + (size_t)(n0 + br + 32) * KDIM + ag * 8;
    const float* pb2 = B + (size_t)(n0 + br + 64) * KDIM + ag * 8;
    const float* pb3 = B + (size_t)(n0 + br + 96) * KDIM + ag * 8;
    const int wB = br * 64 + (ag ^ (br & 7)) * 8;

    f32x4 acc[4][2] = {};
    float4 la0, la1, la2, la3, lb0, lb1, lb2, lb3, lb4, lb5, lb6, lb7;

#define GLOAD(k0)                                                \
    la0 = *reinterpret_cast<const float4*>(pa0 + (k0));          \
    la1 = *reinterpret_cast<const float4*>(pa0 + (k0) + 4);      \
    la2 = *reinterpret_cast<const float4*>(pa1 + (k0));          \
    la3 = *reinterpret_cast<const float4*>(pa1 + (k0) + 4);      \
    lb0 = *reinterpret_cast<const float4*>(pb0 + (k0));          \
    lb1 = *reinterpret_cast<const float4*>(pb0 + (k0) + 4);      \
    lb2 = *reinterpret_cast<const float4*>(pb1 + (k0));          \
    lb3 = *reinterpret_cast<const float4*>(pb1 + (k0) + 4);      \
    lb4 = *reinterpret_cast<const float4*>(pb2 + (k0));          \
    lb5 = *reinterpret_cast<const float4*>(pb2 + (k0) + 4);      \
    lb6 = *reinterpret_cast<const float4*>(pb3 + (k0));          \
    lb7 = *reinterpret_cast<const float4*>(pb3 + (k0) + 4);

#define LWRITE(buf)                                                          \
    *reinterpret_cast<bf16x8*>(lA[buf] + wA0) = cvt8(la0, la1);              \
    *reinterpret_cast<bf16x8*>(lA[buf] + wA1) = cvt8(la2, la3);              \
    *reinterpret_cast<bf16x8*>(lB[buf] + wB) = cvt8(lb0, lb1);               \
    *reinterpret_cast<bf16x8*>(lB[buf] + wB + 32 * 64) = cvt8(lb2, lb3);     \
    *reinterpret_cast<bf16x8*>(lB[buf] + wB + 64 * 64) = cvt8(lb4, lb5);     \
    *reinterpret_cast<bf16x8*>(lB[buf] + wB + 96 * 64) = cvt8(lb6, lb7);

    GLOAD(0)
    LWRITE(0)
    __syncthreads();
    int cur = 0;
#pragma unroll
    for (int kt = 0; kt < 8; kt++) {
        if (kt + 1 < 8) { GLOAD((kt + 1) * 64) }

        bf16x8 af[4][2], bfr[2][2];
#pragma unroll
        for (int i = 0; i < 4; i++)
#pragma unroll
            for (int h = 0; h < 2; h++) {
                int row = i * 16 + (lane & 15);
                int s = (lane >> 4) + h * 4;
                af[i][h] = *reinterpret_cast<const bf16x8*>(
                    lA[cur] + (size_t)row * 64 + (size_t)(s ^ (row & 7)) * 8);
            }
#pragma unroll
        for (int j = 0; j < 2; j++)
#pragma unroll
            for (int h = 0; h < 2; h++) {
                int row = wc * 32 + j * 16 + (lane & 15);
                int s = (lane >> 4) + h * 4;
                bfr[j][h] = *reinterpret_cast<const bf16x8*>(
                    lB[cur] + (size_t)row * 64 + (size_t)(s ^ (row & 7)) * 8);
            }
#pragma unroll
        for (int h = 0; h < 2; h++)
#pragma unroll
            for (int i = 0; i < 4; i++)
#pragma unroll
                for (int j = 0; j < 2; j++)
                    acc[i][j] = __builtin_amdgcn_mfma_f32_16x16x32_bf16(af[i][h], bfr[j][h], acc[i][j], 0, 0, 0);

        if (kt + 1 < 8) { LWRITE(cur ^ 1) }
        __syncthreads();
        cur ^= 1;
    }

#pragma unroll
    for (int i = 0; i < 4; i++) {
#pragma unroll
        for (int r = 0; r < 4; r++) {
            int row = m0 + i * 16 + (lane >> 4) * 4 + r;
            if (row < M) {
#pragma unroll
                for (int j = 0; j < 2; j++) {
                    int col = n0 + wc * 32 + j * 16 + (lane & 15);
                    C[(size_t)row * NDIM + col] = f2bf(acc[i][j][r]);
                }
            }
        }
    }
}

// per-edge accumulate: 8 bf16x2 words -> 8 fp32 channels
#define ACC8(P, vv, uu)                                      \
    P[0] += (vv) * __uint_as_float((uu).x << 16);            \
    P[1] += (vv) * __uint_as_float((uu).x & 0xffff0000u);    \
    P[2] += (vv) * __uint_as_float((uu).y << 16);            \
    P[3] += (vv) * __uint_as_float((uu).y & 0xffff0000u);    \
    P[4] += (vv) * __uint_as_float((uu).z << 16);            \
    P[5] += (vv) * __uint_as_float((uu).z & 0xffff0000u);    \
    P[6] += (vv) * __uint_as_float((uu).w << 16);            \
    P[7] += (vv) * __uint_as_float((uu).w & 0xffff0000u);

// L1-bypassing gather: agent-scope relaxed atomic loads emit sc0 (read around
// L1, cache in L2). Theory: the random 1KB-row gather has ~0% L1 hit and is
// serialized in the TCP miss pipeline; sc0 skips it.
__device__ __forceinline__ uint4 gat(const unsigned short* xb, int c, int lane) {
    const unsigned long long* p =
        reinterpret_cast<const unsigned long long*>(xb + (size_t)c * NDIM + lane * 8);
    unsigned long long a = __hip_atomic_load(p, __ATOMIC_RELAXED, __HIP_MEMORY_SCOPE_AGENT);
    unsigned long long b = __hip_atomic_load(p + 1, __ATOMIC_RELAXED, __HIP_MEMORY_SCOPE_AGENT);
    uint4 r;
    r.x = (unsigned)a; r.y = (unsigned)(a >> 32);
    r.z = (unsigned)b; r.w = (unsigned)(b >> 32);
    return r;
}
#define GATHER(c) gat(xb, (c), lane)

// ---- COO spmm (row_ptr precomputed) + bias + PReLU, bf16 sc0 gather ----
__global__ __launch_bounds__(256) void spmm_prelu_kernel(
    const unsigned short* __restrict__ xb,  // [NNODES][512] bf16
    const float* __restrict__ vals,         // [E]
    const int* __restrict__ row_ptr,        // [NNODES+1]
    const int* __restrict__ cols,           // [E]
    const float* __restrict__ bias,         // [512]
    const float* __restrict__ prelu_a,      // [1]
    float* __restrict__ out) {
    const int lane = threadIdx.x & 63;
    const int gw = (blockIdx.x * 256 + threadIdx.x) >> 6;  // 0..4999
    const int nd0 = gw, nd1 = gw + 5000;

    const int s0 = __builtin_amdgcn_readfirstlane(row_ptr[nd0]);
    const int e0 = __builtin_amdgcn_readfirstlane(row_ptr[nd0 + 1]);
    const int s1 = __builtin_amdgcn_readfirstlane(row_ptr[nd1]);
    const int e1 = __builtin_amdgcn_readfirstlane(row_ptr[nd1 + 1]);

    float p[8] = {}, q[8] = {};

    int i0 = s0, i1 = s1;
    while ((i0 + 4 <= e0) && (i1 + 4 <= e1)) {
        float v00 = vals[i0], v01 = vals[i0 + 1], v02 = vals[i0 + 2], v03 = vals[i0 + 3];
        int   c00 = cols[i0], c01 = cols[i0 + 1], c02 = cols[i0 + 2], c03 = cols[i0 + 3];
        float v10 = vals[i1], v11 = vals[i1 + 1], v12 = vals[i1 + 2], v13 = vals[i1 + 3];
        int   c10 = cols[i1], c11 = cols[i1 + 1], c12 = cols[i1 + 2], c13 = cols[i1 + 3];
        uint4 u00 = GATHER(c00), u01 = GATHER(c01), u02 = GATHER(c02), u03 = GATHER(c03);
        uint4 u10 = GATHER(c10), u11 = GATHER(c11), u12 = GATHER(c12), u13 = GATHER(c13);
        ACC8(p, v00, u00) ACC8(p, v01, u01) ACC8(p, v02, u02) ACC8(p, v03, u03)
        ACC8(q, v10, u10) ACC8(q, v11, u11) ACC8(q, v12, u12) ACC8(q, v13, u13)
        i0 += 4; i1 += 4;
    }
    for (; i0 + 4 <= e0; i0 += 4) {
        float v0 = vals[i0], v1 = vals[i0 + 1], v2 = vals[i0 + 2], v3 = vals[i0 + 3];
        uint4 u0 = GATHER(cols[i0]), u1 = GATHER(cols[i0 + 1]);
        uint4 u2 = GATHER(cols[i0 + 2]), u3 = GATHER(cols[i0 + 3]);
        ACC8(p, v0, u0) ACC8(p, v1, u1) ACC8(p, v2, u2) ACC8(p, v3, u3)
    }
    for (; i0 < e0; i0++) {
        float v0 = vals[i0]; uint4 u0 = GATHER(cols[i0]);
        ACC8(p, v0, u0)
    }
    for (; i1 + 4 <= e1; i1 += 4) {
        float v0 = vals[i1], v1 = vals[i1 + 1], v2 = vals[i1 + 2], v3 = vals[i1 + 3];
        uint4 u0 = GATHER(cols[i1]), u1 = GATHER(cols[i1 + 1]);
        uint4 u2 = GATHER(cols[i1 + 2]), u3 = GATHER(cols[i1 + 3]);
        ACC8(q, v0, u0) ACC8(q, v1, u1) ACC8(q, v2, u2) ACC8(q, v3, u3)
    }
    for (; i1 < e1; i1++) {
        float v0 = vals[i1]; uint4 u0 = GATHER(cols[i1]);
        ACC8(q, v0, u0)
    }

    const float4* b4 = reinterpret_cast<const float4*>(bias + lane * 8);
    const float4 bA = b4[0], bB = b4[1];
    const float al = prelu_a[0];

#define EPILOGUE(P, node)                                                        \
    {                                                                            \
        float o0 = P[0] + bA.x, o1 = P[1] + bA.y, o2 = P[2] + bA.z, o3 = P[3] + bA.w; \
        float o4 = P[4] + bB.x, o5 = P[5] + bB.y, o6 = P[6] + bB.z, o7 = P[7] + bB.w; \
        o0 = (o0 >= 0.f) ? o0 : al * o0;                                         \
        o1 = (o1 >= 0.f) ? o1 : al * o1;                                         \
        o2 = (o2 >= 0.f) ? o2 : al * o2;                                         \
        o3 = (o3 >= 0.f) ? o3 : al * o3;                                         \
        o4 = (o4 >= 0.f) ? o4 : al * o4;                                         \
        o5 = (o5 >= 0.f) ? o5 : al * o5;                                         \
        o6 = (o6 >= 0.f) ? o6 : al * o6;                                         \
        o7 = (o7 >= 0.f) ? o7 : al * o7;                                         \
        f32x4 r0; r0[0] = o0; r0[1] = o1; r0[2] = o2; r0[3] = o3;                \
        f32x4 r1; r1[0] = o4; r1[1] = o5; r1[2] = o6; r1[3] = o7;                \
        f32x4* op = reinterpret_cast<f32x4*>(out + (size_t)(node) * NDIM + lane * 8); \
        __builtin_nontemporal_store(r0, op);                                     \
        __builtin_nontemporal_store(r1, op + 1);                                 \
    }

    EPILOGUE(p, nd0)
    EPILOGUE(q, nd1)
}

extern "C" void kernel_launch(void* const* d_in, const int* in_sizes, int n_in,
                              void* d_out, int out_size, void* d_ws, size_t ws_size,
                              hipStream_t stream) {
    const float* x        = (const float*)d_in[0];
    const float* fc_w     = (const float*)d_in[1];
    const float* bias     = (const float*)d_in[2];
    const float* prelu_a  = (const float*)d_in[3];
    const float* adj_vals = (const float*)d_in[4];
    const int*   adj_row  = (const int*)d_in[5];
    const int*   adj_col  = (const int*)d_in[6];
    float* out = (float*)d_out;

    char* ws = (char*)d_ws;
    unsigned short* xfb = (unsigned short*)ws;          // @0,        10,240,000 B
    int* row_ptr        = (int*)(ws + 10240000);        // @10240000,     40,064 B

    gemm_rowptr_kernel<<<GEMM_BLOCKS + RP_BLOCKS, 256, 0, stream>>>(
        x, fc_w, xfb, adj_row, row_ptr, NNODES);

    spmm_prelu_kernel<<<1250, 256, 0, stream>>>(xfb, adj_vals, row_ptr, adj_col,
                                                bias, prelu_a, out);
}